// Round 4
// baseline (2325.068 us; speedup 1.0000x reference)
//
#include <hip/hip_runtime.h>
#include <cstdint>
#include <cstddef>

// ---------------------------------------------------------------------------
// LinearSGD fused pipeline for MI355X (gfx950).  ALL I/O is float32.
// Precision: split-bf16 (hi+lo) at every MFMA:  X = xh + xl (+ ~2^-17 rel),
//   A@B ~= Ah@Bh + Ah@Bl + Al@Bh  (3-term, f32 accum).
// Splits are computed ON THE FLY during LDS staging (no split buffers in ws).
// Workspace (202.4 MB < 210 MB proven-good):
//   q hi/lo (67.1) + k hi/lo (67.1) + v/outs shared f32 (67.1) + eta/theta (1).
// Stages: etatheta | gemm3 q,k (split out), v (f32 out, ->vo) | scan (in-place
//   vo: reads v, writes z) | gemm3 g (f32, reuses k slot) | norm (og split,
//   reuses q slot) | gemm3 out (A = og split) -> d_out f32.
// ---------------------------------------------------------------------------

typedef unsigned short u16b;
typedef __attribute__((ext_vector_type(8))) __bf16 bf16x8;
typedef __attribute__((ext_vector_type(4))) float  f32x4;

__device__ __forceinline__ float bf2f(u16b v){
  union { float f; uint32_t u; } x; x.u = ((uint32_t)v) << 16; return x.f;
}
__device__ __forceinline__ u16b f2bf(float f){
  union { float f; uint32_t u; } x; x.f = f;
  uint32_t r = x.u + 0x7fffu + ((x.u >> 16) & 1u);   // round-to-nearest-even
  return (u16b)(r >> 16);
}
__device__ __forceinline__ f32x4 mfma16(bf16x8 a, bf16x8 b, f32x4 c){
  return __builtin_amdgcn_mfma_f32_16x16x32_bf16(a, b, c, 0, 0, 0);
}

// ---------------------------------------------------------------------------
// Split GEMM: C[M,N] = A[M,Kd] @ B[N,Kd]^T, 3-term split-bf16 MFMA.
// 128x128 tile, 4 waves 2x2, each wave 64x64 = 4x4 MFMA 16x16x32 tiles.
// AMODE 0: A is f32, split during staging.  AMODE 1: A is pre-split (Ah,Al).
// B is always f32, split during staging.
// OUTMODE 0: write (Ch, Cl) bf16 split.  OUTMODE 1: write Cf f32.
// LDS 32 KB.
// ---------------------------------------------------------------------------
template<int AMODE, int OUTMODE>
__global__ __launch_bounds__(256) void gemm3(
    const float* __restrict__ Af,
    const u16b* __restrict__ Ah, const u16b* __restrict__ Al,
    const float* __restrict__ Bf,
    u16b* __restrict__ Ch, u16b* __restrict__ Cl, float* __restrict__ Cf,
    int M, int N, int Kd, float alpha)
{
  __shared__ u16b Ahs[128*32];
  __shared__ u16b Als[128*32];
  __shared__ u16b Bhs[128*32];
  __shared__ u16b Bls[128*32];
  const int m0 = blockIdx.y * 128;
  const int n0 = blockIdx.x * 128;
  const int tid  = threadIdx.x;
  const int wid  = tid >> 6;
  const int lane = tid & 63;
  const int wm = (wid & 1) * 64;
  const int wn = (wid >> 1) * 64;
  const int rw = lane & 15;
  const int kq = (lane >> 4) * 8;

  f32x4 acc[4][4] = {};

  for (int k0 = 0; k0 < Kd; k0 += 32){
    // ---- load (registers), f32 path: 4 float4 per matrix; split path: uint4.
    float4 fb[4];
#pragma unroll
    for (int it = 0; it < 4; it++){
      int idx = it*256 + tid;
      int rr = idx >> 3, c4 = (idx & 7) * 4;
      fb[it] = *(const float4*)(Bf + (size_t)(n0 + rr) * Kd + k0 + c4);
    }
    float4 fa[4];
    uint4  ua[4];
    if constexpr (AMODE == 0){
#pragma unroll
      for (int it = 0; it < 4; it++){
        int idx = it*256 + tid;
        int rr = idx >> 3, c4 = (idx & 7) * 4;
        fa[it] = *(const float4*)(Af + (size_t)(m0 + rr) * Kd + k0 + c4);
      }
    } else {
      int r0 = tid >> 2, c8 = (tid & 3) * 8;
      size_t offA = (size_t)(m0 + r0) * Kd + k0 + c8;
      ua[0] = *(const uint4*)(Ah + offA);
      ua[1] = *(const uint4*)(Ah + offA + (size_t)64*Kd);
      ua[2] = *(const uint4*)(Al + offA);
      ua[3] = *(const uint4*)(Al + offA + (size_t)64*Kd);
    }
    __syncthreads();                       // prev-iter LDS reads done
    // ---- store to LDS (split f32 -> hi/lo)
#pragma unroll
    for (int it = 0; it < 4; it++){
      int idx = it*256 + tid;
      int rr = idx >> 3, c4 = (idx & 7) * 4;
      float f[4] = {fb[it].x, fb[it].y, fb[it].z, fb[it].w};
      u16b h[4], l[4];
#pragma unroll
      for (int j = 0; j < 4; j++){ h[j] = f2bf(f[j]); l[j] = f2bf(f[j] - bf2f(h[j])); }
      *(uint2*)&Bhs[rr*32 + c4] = *(const uint2*)h;
      *(uint2*)&Bls[rr*32 + c4] = *(const uint2*)l;
    }
    if constexpr (AMODE == 0){
#pragma unroll
      for (int it = 0; it < 4; it++){
        int idx = it*256 + tid;
        int rr = idx >> 3, c4 = (idx & 7) * 4;
        float f[4] = {fa[it].x, fa[it].y, fa[it].z, fa[it].w};
        u16b h[4], l[4];
#pragma unroll
        for (int j = 0; j < 4; j++){ h[j] = f2bf(f[j]); l[j] = f2bf(f[j] - bf2f(h[j])); }
        *(uint2*)&Ahs[rr*32 + c4] = *(const uint2*)h;
        *(uint2*)&Als[rr*32 + c4] = *(const uint2*)l;
      }
    } else {
      int r0 = tid >> 2, c8 = (tid & 3) * 8;
      *(uint4*)&Ahs[r0*32 + c8]      = ua[0];
      *(uint4*)&Ahs[(64+r0)*32 + c8] = ua[1];
      *(uint4*)&Als[r0*32 + c8]      = ua[2];
      *(uint4*)&Als[(64+r0)*32 + c8] = ua[3];
    }
    __syncthreads();

    bf16x8 afh[4], afl[4], bfh[4], bfl[4];
#pragma unroll
    for (int i = 0; i < 4; i++){
      afh[i] = *(const bf16x8*)&Ahs[(wm + i*16 + rw)*32 + kq];
      afl[i] = *(const bf16x8*)&Als[(wm + i*16 + rw)*32 + kq];
    }
#pragma unroll
    for (int j = 0; j < 4; j++){
      bfh[j] = *(const bf16x8*)&Bhs[(wn + j*16 + rw)*32 + kq];
      bfl[j] = *(const bf16x8*)&Bls[(wn + j*16 + rw)*32 + kq];
    }
#pragma unroll
    for (int i = 0; i < 4; i++)
#pragma unroll
      for (int j = 0; j < 4; j++){
        f32x4 t = mfma16(afl[i], bfh[j], acc[i][j]);
        t = mfma16(afh[i], bfl[j], t);
        acc[i][j] = mfma16(afh[i], bfh[j], t);
      }
  }

  // C/D layout: col = lane&15, row = (lane>>4)*4 + reg
  const int col  = lane & 15;
  const int quad = lane >> 4;
#pragma unroll
  for (int i = 0; i < 4; i++)
#pragma unroll
    for (int j = 0; j < 4; j++)
#pragma unroll
      for (int r = 0; r < 4; r++){
        int row = m0 + wm + i*16 + quad*4 + r;
        int c   = n0 + wn + j*16 + col;
        float v = acc[i][j][r] * alpha;
        if constexpr (OUTMODE == 0){
          u16b h = f2bf(v);
          Ch[(size_t)row * N + c] = h;
          Cl[(size_t)row * N + c] = f2bf(v - bf2f(h));
        } else {
          Cf[(size_t)row * N + c] = v;
        }
      }
}

// ---------------------------------------------------------------------------
// eta/theta skinny projection (pure f32, exact): per (b,t) row, 32 dots.
// ---------------------------------------------------------------------------
__global__ __launch_bounds__(256) void etatheta_kernel(
    const float* __restrict__ x, const float* __restrict__ Weta,
    const float* __restrict__ Wtheta, float* __restrict__ eta, float* __restrict__ theta)
{
  __shared__ float xr[2048];
  const int bt = blockIdx.x;
  const int b = bt >> 12, t = bt & 4095;
  const float* xp = x + (size_t)bt * 2048;
  for (int i = threadIdx.x; i < 2048; i += 256) xr[i] = xp[i];
  __syncthreads();
  const int wid = threadIdx.x >> 6, lane = threadIdx.x & 63;
  for (int oi = 0; oi < 8; oi++){
    int og = wid*8 + oi;
    const float* wrow = (og < 16) ? (Weta + (size_t)og*2048)
                                  : (Wtheta + (size_t)(og-16)*2048);
    float acc = 0.f;
    for (int d = lane; d < 2048; d += 64) acc += xr[d] * wrow[d];
#pragma unroll
    for (int off = 32; off; off >>= 1) acc += __shfl_down(acc, off);
    if (lane == 0){
      float s = 1.f / (1.f + expf(-acc));
      if (og < 16) eta  [((size_t)(b*16 + og     ))*4096 + t] = s;
      else         theta[((size_t)(b*16 + og - 16))*4096 + t] = 0.1f * s;
    }
  }
}

// ---------------------------------------------------------------------------
// Chunk scan, split-bf16. Grid: (B*H, V/32). Block 256 = 4 waves. LDS 85 KB.
//   e   = kc @ W^T - vc      (k split LDS, W split LDS, v read from global)
//   qk  = qc @ kc^T          (q split from GLOBAL, k split LDS)
//   zq  = qc @ W^T
//   S   = qk * beta * theta[j] (tril), split store
//   z   = exp(lec)[t]*zq - S @ e  -> written IN PLACE over v (same indices)
//   dw  = (beta_last*theta*e)^T @ kc
//   W  <- W*exp(lec[63]) - dw   (split-only state Wh+Wl, ~2^-17 rel)
// ---------------------------------------------------------------------------
__global__ __launch_bounds__(256) void scan_kernel(
    const u16b* __restrict__ qh, const u16b* __restrict__ ql,
    const u16b* __restrict__ kh, const u16b* __restrict__ kl,
    const float* __restrict__ eta, const float* __restrict__ theta,
    float* vo)                                     // v in, outs out (aliased)
{
  __shared__ u16b kh_s[64*128], kl_s[64*128];
  __shared__ u16b Wh[32*128], Wl[32*128];
  __shared__ u16b eh_s [32*72], el_s [32*72];
  __shared__ u16b ewh_s[32*72], ewl_s[32*72];
  __shared__ u16b Sh_s [64*72], Sl_s [64*72];
  __shared__ float lec_s[64], elt_s[64], thj_s[64], wt_s[64];

  const int bh = blockIdx.x;
  const int b = bh >> 4, h = bh & 15;
  const int v0 = blockIdx.y * 32;
  const int tid  = threadIdx.x;
  const int wid  = tid >> 6;
  const int lane = tid & 63;
  const int rw = lane & 15;
  const int kq = (lane >> 4) * 8;
  const int ccol  = lane & 15;
  const int cquad = lane >> 4;

  for (int i = tid; i < 32*128; i += 256){ Wh[i] = 0; Wl[i] = 0; }

  const float* etap = eta   + (size_t)bh * 4096;
  const float* thp  = theta + (size_t)bh * 4096;
  const size_t rowbase = (size_t)b * 4096;
  // per-lane global q fragment row pointers (A-operand row = wid*16 + rw)
  const size_t qrow = (rowbase + wid*16 + rw) * 2048 + (size_t)h*128;

  for (int n = 0; n < 64; n++){
    const int tbase = n * 64;
    __syncthreads();                         // prev-iter reads + W update done

    // ---- stage k (hi/lo), coalesced 16B/lane
#pragma unroll
    for (int it = 0; it < 4; it++){
      int idx = it*256 + tid;
      int r = idx >> 4, c8 = (idx & 15) * 8;
      size_t gq = (rowbase + tbase + r) * 2048 + (size_t)h*128 + c8;
      *(uint4*)&kh_s[r*128 + c8] = *(const uint4*)&kh[gq];
      *(uint4*)&kl_s[r*128 + c8] = *(const uint4*)&kl[gq];
    }
    // ---- q fragments straight from global (L3-warm)
    bf16x8 qah[4], qal[4];
#pragma unroll
    for (int ks = 0; ks < 4; ks++){
      qah[ks] = *(const bf16x8*)(qh + qrow + (size_t)tbase*2048 + ks*32 + kq);
      qal[ks] = *(const bf16x8*)(ql + qrow + (size_t)tbase*2048 + ks*32 + kq);
    }
    // ---- decay bookkeeping (wave 0, lane = t)
    if (wid == 0){
      float le = logf(fmaxf(etap[tbase + lane], 1e-8f));
      float cum = le;
#pragma unroll
      for (int off = 1; off < 64; off <<= 1){
        float o = __shfl_up(cum, off);
        if (lane >= off) cum += o;
      }
      float lec63 = __shfl(cum, 63);
      lec_s[lane] = cum;
      elt_s[lane] = expf(cum);
      float th = thp[tbase + lane];
      thj_s[lane] = th;
      wt_s[lane]  = expf(lec63 - cum) * th;  // beta[last, t] * theta[t]
    }
    __syncthreads();

    // ---- e = kc @ W^T (3-term split)
    f32x4 eacc[2] = {};
#pragma unroll
    for (int ks = 0; ks < 4; ks++){
      bf16x8 ah = *(const bf16x8*)&kh_s[(wid*16 + rw)*128 + ks*32 + kq];
      bf16x8 al = *(const bf16x8*)&kl_s[(wid*16 + rw)*128 + ks*32 + kq];
#pragma unroll
      for (int j = 0; j < 2; j++){
        bf16x8 bh_ = *(const bf16x8*)&Wh[(j*16 + rw)*128 + ks*32 + kq];
        bf16x8 bl_ = *(const bf16x8*)&Wl[(j*16 + rw)*128 + ks*32 + kq];
        f32x4 t = mfma16(al, bh_, eacc[j]);
        t = mfma16(ah, bl_, t);
        eacc[j] = mfma16(ah, bh_, t);
      }
    }
    // ---- qk (split) and zq (split), q frags from registers
    f32x4 qkacc[4] = {};
    f32x4 zqacc[2] = {};
#pragma unroll
    for (int ks = 0; ks < 4; ks++){
#pragma unroll
      for (int j4 = 0; j4 < 4; j4++){
        bf16x8 bh_ = *(const bf16x8*)&kh_s[(j4*16 + rw)*128 + ks*32 + kq];
        bf16x8 bl_ = *(const bf16x8*)&kl_s[(j4*16 + rw)*128 + ks*32 + kq];
        f32x4 t = mfma16(qal[ks], bh_, qkacc[j4]);
        t = mfma16(qah[ks], bl_, t);
        qkacc[j4] = mfma16(qah[ks], bh_, t);
      }
#pragma unroll
      for (int j = 0; j < 2; j++){
        bf16x8 bh_ = *(const bf16x8*)&Wh[(j*16 + rw)*128 + ks*32 + kq];
        bf16x8 bl_ = *(const bf16x8*)&Wl[(j*16 + rw)*128 + ks*32 + kq];
        f32x4 t = mfma16(qal[ks], bh_, zqacc[j]);
        t = mfma16(qah[ks], bl_, t);
        zqacc[j] = mfma16(qah[ks], bh_, t);
      }
    }
    // ---- e finalize: subtract v (global read), split-store e and ew
#pragma unroll
    for (int j = 0; j < 2; j++)
#pragma unroll
      for (int r = 0; r < 4; r++){
        int t  = wid*16 + cquad*4 + r;
        int vv = j*16 + ccol;
        float vval = vo[((rowbase + tbase + t)*16 + h)*128 + v0 + vv];
        float e = eacc[j][r] - vval;
        u16b eh = f2bf(e);
        eh_s[vv*72 + t] = eh;
        el_s[vv*72 + t] = f2bf(e - bf2f(eh));
        float ew = e * wt_s[t];
        u16b ewh = f2bf(ew);
        ewh_s[vv*72 + t] = ewh;
        ewl_s[vv*72 + t] = f2bf(ew - bf2f(ewh));
      }
    // ---- S = qk * beta * theta[j], tril; split store
#pragma unroll
    for (int j4 = 0; j4 < 4; j4++)
#pragma unroll
      for (int r = 0; r < 4; r++){
        int t  = wid*16 + cquad*4 + r;
        int jj = j4*16 + ccol;
        float s = 0.f;
        if (jj <= t)
          s = qkacc[j4][r] * __expf(fminf(lec_s[t] - lec_s[jj], 0.f)) * thj_s[jj];
        u16b sh = f2bf(s);
        Sh_s[t*72 + jj] = sh;
        Sl_s[t*72 + jj] = f2bf(s - bf2f(sh));
      }
    __syncthreads();                         // e/ew/S visible; W reads done

    // ---- Se = S @ e (split)
    f32x4 seacc[2] = {};
#pragma unroll
    for (int ks2 = 0; ks2 < 2; ks2++){
      bf16x8 ah = *(const bf16x8*)&Sh_s[(wid*16 + rw)*72 + ks2*32 + kq];
      bf16x8 al = *(const bf16x8*)&Sl_s[(wid*16 + rw)*72 + ks2*32 + kq];
#pragma unroll
      for (int j = 0; j < 2; j++){
        bf16x8 bh_ = *(const bf16x8*)&eh_s[(j*16 + rw)*72 + ks2*32 + kq];
        bf16x8 bl_ = *(const bf16x8*)&el_s[(j*16 + rw)*72 + ks2*32 + kq];
        f32x4 t = mfma16(al, bh_, seacc[j]);
        t = mfma16(ah, bl_, t);
        seacc[j] = mfma16(ah, bh_, t);
      }
    }
    // ---- z -> vo in place (same lane wrote/read identical indices)
#pragma unroll
    for (int j = 0; j < 2; j++)
#pragma unroll
      for (int r = 0; r < 4; r++){
        int t  = wid*16 + cquad*4 + r;
        int vv = j*16 + ccol;
        float z = elt_s[t]*zqacc[j][r] - seacc[j][r];
        vo[((rowbase + tbase + t)*16 + h)*128 + v0 + vv] = z;
      }
    // ---- dw: M=32 (v), N=128 (k, wave-split), K=64 (t); split ew x split k
    f32x4 dwacc[2][2] = {};
#pragma unroll
    for (int ks2 = 0; ks2 < 2; ks2++){
      bf16x8 amh0 = *(const bf16x8*)&ewh_s[(     rw)*72 + ks2*32 + kq];
      bf16x8 aml0 = *(const bf16x8*)&ewl_s[(     rw)*72 + ks2*32 + kq];
      bf16x8 amh1 = *(const bf16x8*)&ewh_s[(16 + rw)*72 + ks2*32 + kq];
      bf16x8 aml1 = *(const bf16x8*)&ewl_s[(16 + rw)*72 + ks2*32 + kq];
#pragma unroll
      for (int nj = 0; nj < 2; nj++){
        union { bf16x8 v; u16b s[8]; } bkh, bkl;
        int kcol = wid*32 + nj*16 + rw;
#pragma unroll
        for (int i = 0; i < 8; i++){
          int trow = (ks2*32 + kq + i)*128 + kcol;
          bkh.s[i] = kh_s[trow];
          bkl.s[i] = kl_s[trow];
        }
        f32x4 t0 = mfma16(aml0, bkh.v, dwacc[0][nj]);
        t0 = mfma16(amh0, bkl.v, t0);
        dwacc[0][nj] = mfma16(amh0, bkh.v, t0);
        f32x4 t1 = mfma16(aml1, bkh.v, dwacc[1][nj]);
        t1 = mfma16(amh1, bkl.v, t1);
        dwacc[1][nj] = mfma16(amh1, bkh.v, t1);
      }
    }
    // ---- W <- W*exp(lec[63]) - dw  (disjoint per lane; split-only state)
    float dfac = elt_s[63];
#pragma unroll
    for (int mi = 0; mi < 2; mi++)
#pragma unroll
      for (int nj = 0; nj < 2; nj++)
#pragma unroll
        for (int r = 0; r < 4; r++){
          int vv = mi*16 + cquad*4 + r;
          int kk = wid*32 + nj*16 + ccol;
          int idx = vv*128 + kk;
          float w = bf2f(Wh[idx]) + bf2f(Wl[idx]);
          w = w*dfac - dwacc[mi][nj][r];
          u16b wh_ = f2bf(w);
          Wh[idx] = wh_;
          Wl[idx] = f2bf(w - bf2f(wh_));
        }
  }
}

// ---------------------------------------------------------------------------
// Gated RMSNorm, f32 in -> split bf16 out.
// ---------------------------------------------------------------------------
__global__ __launch_bounds__(256) void norm_kernel(
    const float* __restrict__ outs, const float* __restrict__ g,
    const float* __restrict__ nw, u16b* __restrict__ ogh, u16b* __restrict__ ogl)
{
  const int bt = blockIdx.x;
  const int tid = threadIdx.x;
  size_t base = (size_t)bt*2048 + (size_t)tid*8;
  float4 x0 = *(const float4*)(outs + base);
  float4 x1 = *(const float4*)(outs + base + 4);
  float x[8] = {x0.x,x0.y,x0.z,x0.w,x1.x,x1.y,x1.z,x1.w};
  float ss = 0.f;
#pragma unroll
  for (int i = 0; i < 8; i++) ss += x[i]*x[i];
#pragma unroll
  for (int off = 1; off < 16; off <<= 1) ss += __shfl_xor(ss, off);  // 16-lane head
  float rs = rsqrtf(ss*(1.f/128.f) + 1e-5f);
  float4 g0 = *(const float4*)(g + base);
  float4 g1 = *(const float4*)(g + base + 4);
  float gg[8] = {g0.x,g0.y,g0.z,g0.w,g1.x,g1.y,g1.z,g1.w};
  int nwb = (tid & 15)*8;
  u16b oh[8], ol[8];
#pragma unroll
  for (int i = 0; i < 8; i++){
    float sig = 1.f / (1.f + __expf(-gg[i]));
    float v = x[i]*rs*nw[nwb+i]*gg[i]*sig;
    oh[i] = f2bf(v);
    ol[i] = f2bf(v - bf2f(oh[i]));
  }
  *(uint4*)(ogh + base) = *(const uint4*)oh;
  *(uint4*)(ogl + base) = *(const uint4*)ol;
}

// ---------------------------------------------------------------------------
extern "C" void kernel_launch(void* const* d_in, const int* in_sizes, int n_in,
                              void* d_out, int out_size, void* d_ws, size_t ws_size,
                              hipStream_t stream)
{
  (void)in_sizes; (void)n_in; (void)out_size; (void)ws_size;
  const float* x    = (const float*)d_in[0];
  const float* Wq   = (const float*)d_in[1];
  const float* Wk   = (const float*)d_in[2];
  const float* Wv   = (const float*)d_in[3];
  const float* Weta = (const float*)d_in[4];
  const float* Wth  = (const float*)d_in[5];
  const float* Wg   = (const float*)d_in[6];
  const float* nw   = (const float*)d_in[7];
  const float* Wo   = (const float*)d_in[8];
  float* out = (float*)d_out;

  const size_t SZ = (size_t)8192*2048;      // activation elems
  u16b* ws = (u16b*)d_ws;
  u16b* qhb = ws;            u16b* qlb = qhb + SZ;
  u16b* khb = qlb + SZ;      u16b* klb = khb + SZ;
  float* vob  = (float*)(klb + SZ);         // v, then outs in place
  float* etab = vob + SZ;
  float* thb  = etab + (size_t)2*16*4096;
  float* gfb  = (float*)khb;                // g f32 after scan (spans kh+kl)
  u16b* ogh = qhb; u16b* ogl = qlb;         // og reuses q slot

  dim3 gg(16, 64);
  etatheta_kernel<<<8192, 256, 0, stream>>>(x, Weta, Wth, etab, thb);
  gemm3<0,0><<<gg, 256, 0, stream>>>(x, nullptr, nullptr, Wq, qhb, qlb, nullptr,
                                     8192, 2048, 2048, 0.08838834764831843f);
  gemm3<0,0><<<gg, 256, 0, stream>>>(x, nullptr, nullptr, Wk, khb, klb, nullptr,
                                     8192, 2048, 2048, 1.f);
  gemm3<0,1><<<gg, 256, 0, stream>>>(x, nullptr, nullptr, Wv, nullptr, nullptr, vob,
                                     8192, 2048, 2048, 1.f);
  scan_kernel<<<dim3(32,4), 256, 0, stream>>>(qhb, qlb, khb, klb, etab, thb, vob);
  gemm3<0,1><<<gg, 256, 0, stream>>>(x, nullptr, nullptr, Wg, nullptr, nullptr, gfb,
                                     8192, 2048, 2048, 1.f);
  norm_kernel<<<8192, 256, 0, stream>>>(vob, gfb, nw, ogh, ogl);
  gemm3<1,1><<<gg, 256, 0, stream>>>(nullptr, ogh, ogl, Wo, nullptr, nullptr, out,
                                     8192, 2048, 2048, 1.f);
}

// Round 5
// 2132.614 us; speedup vs baseline: 1.0902x; 1.0902x over previous
//
#include <hip/hip_runtime.h>
#include <cstdint>
#include <cstddef>

// ---------------------------------------------------------------------------
// LinearSGD fused pipeline for MI355X (gfx950).  ALL I/O is float32.
// Precision: split-bf16 (hi+lo) at every MFMA (truncation split:
//   hi = trunc_bf16(x), lo = trunc_bf16(x - hi), |err| <= 2^-16 |x|),
//   A@B ~= Ah@Bh + Ah@Bl + Al@Bh  (3-term, f32 accum).
// Stages: etatheta | decay precompute | gemm3 q,k (split out), v (f32)
//   | scan v2 (512 thr, kT in LDS, v staged, in-place vo) | gemm3 g
//   | norm | gemm3 out -> d_out f32.
// Workspace ~204 MB (< 210.6 MB proven in round 2).
// ---------------------------------------------------------------------------

typedef unsigned short u16b;
typedef __attribute__((ext_vector_type(8))) __bf16 bf16x8;
typedef __attribute__((ext_vector_type(4))) float  f32x4;

__device__ __forceinline__ float bf2f(u16b v){
  union { float f; uint32_t u; } x; x.u = ((uint32_t)v) << 16; return x.f;
}
// truncation-based split: cheap (no rounding chains), hi+lo ~ f to 2^-16
__device__ __forceinline__ void split2(float f, u16b& h, u16b& l){
  uint32_t u = __float_as_uint(f);
  float hf = __uint_as_float(u & 0xFFFF0000u);
  h = (u16b)(u >> 16);
  l = (u16b)(__float_as_uint(f - hf) >> 16);
}
__device__ __forceinline__ f32x4 mfma16(bf16x8 a, bf16x8 b, f32x4 c){
  return __builtin_amdgcn_mfma_f32_16x16x32_bf16(a, b, c, 0, 0, 0);
}

// ---------------------------------------------------------------------------
// Split GEMM: C[M,N] = A[M,Kd] @ B[N,Kd]^T, 3-term split-bf16 MFMA.
// 128x128 tile, 4 waves 2x2, each wave 64x64 = 4x4 MFMA 16x16x32 tiles.
// AMODE 0: A f32 (split during staging).  AMODE 1: A pre-split (Ah,Al).
// OUTMODE 0: write (Ch, Cl) split.  OUTMODE 1: write Cf f32.
// ---------------------------------------------------------------------------
template<int AMODE, int OUTMODE>
__global__ __launch_bounds__(256) void gemm3(
    const float* __restrict__ Af,
    const u16b* __restrict__ Ah, const u16b* __restrict__ Al,
    const float* __restrict__ Bf,
    u16b* __restrict__ Ch, u16b* __restrict__ Cl, float* __restrict__ Cf,
    int M, int N, int Kd, float alpha)
{
  __shared__ u16b Ahs[128*32];
  __shared__ u16b Als[128*32];
  __shared__ u16b Bhs[128*32];
  __shared__ u16b Bls[128*32];
  const int m0 = blockIdx.y * 128;
  const int n0 = blockIdx.x * 128;
  const int tid  = threadIdx.x;
  const int wid  = tid >> 6;
  const int lane = tid & 63;
  const int wm = (wid & 1) * 64;
  const int wn = (wid >> 1) * 64;
  const int rw = lane & 15;
  const int kq = (lane >> 4) * 8;

  f32x4 acc[4][4] = {};

  for (int k0 = 0; k0 < Kd; k0 += 32){
    float4 fb[4];
#pragma unroll
    for (int it = 0; it < 4; it++){
      int idx = it*256 + tid;
      int rr = idx >> 3, c4 = (idx & 7) * 4;
      fb[it] = *(const float4*)(Bf + (size_t)(n0 + rr) * Kd + k0 + c4);
    }
    float4 fa[4];
    uint4  ua[4];
    if constexpr (AMODE == 0){
#pragma unroll
      for (int it = 0; it < 4; it++){
        int idx = it*256 + tid;
        int rr = idx >> 3, c4 = (idx & 7) * 4;
        fa[it] = *(const float4*)(Af + (size_t)(m0 + rr) * Kd + k0 + c4);
      }
    } else {
      int r0 = tid >> 2, c8 = (tid & 3) * 8;
      size_t offA = (size_t)(m0 + r0) * Kd + k0 + c8;
      ua[0] = *(const uint4*)(Ah + offA);
      ua[1] = *(const uint4*)(Ah + offA + (size_t)64*Kd);
      ua[2] = *(const uint4*)(Al + offA);
      ua[3] = *(const uint4*)(Al + offA + (size_t)64*Kd);
    }
    __syncthreads();                       // prev-iter LDS reads done
#pragma unroll
    for (int it = 0; it < 4; it++){
      int idx = it*256 + tid;
      int rr = idx >> 3, c4 = (idx & 7) * 4;
      float f[4] = {fb[it].x, fb[it].y, fb[it].z, fb[it].w};
      u16b h[4], l[4];
#pragma unroll
      for (int j = 0; j < 4; j++) split2(f[j], h[j], l[j]);
      *(uint2*)&Bhs[rr*32 + c4] = *(const uint2*)h;
      *(uint2*)&Bls[rr*32 + c4] = *(const uint2*)l;
    }
    if constexpr (AMODE == 0){
#pragma unroll
      for (int it = 0; it < 4; it++){
        int idx = it*256 + tid;
        int rr = idx >> 3, c4 = (idx & 7) * 4;
        float f[4] = {fa[it].x, fa[it].y, fa[it].z, fa[it].w};
        u16b h[4], l[4];
#pragma unroll
        for (int j = 0; j < 4; j++) split2(f[j], h[j], l[j]);
        *(uint2*)&Ahs[rr*32 + c4] = *(const uint2*)h;
        *(uint2*)&Als[rr*32 + c4] = *(const uint2*)l;
      }
    } else {
      int r0 = tid >> 2, c8 = (tid & 3) * 8;
      *(uint4*)&Ahs[r0*32 + c8]      = ua[0];
      *(uint4*)&Ahs[(64+r0)*32 + c8] = ua[1];
      *(uint4*)&Als[r0*32 + c8]      = ua[2];
      *(uint4*)&Als[(64+r0)*32 + c8] = ua[3];
    }
    __syncthreads();

    bf16x8 afh[4], afl[4], bfh[4], bfl[4];
#pragma unroll
    for (int i = 0; i < 4; i++){
      afh[i] = *(const bf16x8*)&Ahs[(wm + i*16 + rw)*32 + kq];
      afl[i] = *(const bf16x8*)&Als[(wm + i*16 + rw)*32 + kq];
    }
#pragma unroll
    for (int j = 0; j < 4; j++){
      bfh[j] = *(const bf16x8*)&Bhs[(wn + j*16 + rw)*32 + kq];
      bfl[j] = *(const bf16x8*)&Bls[(wn + j*16 + rw)*32 + kq];
    }
#pragma unroll
    for (int i = 0; i < 4; i++)
#pragma unroll
      for (int j = 0; j < 4; j++){
        f32x4 t = mfma16(afl[i], bfh[j], acc[i][j]);
        t = mfma16(afh[i], bfl[j], t);
        acc[i][j] = mfma16(afh[i], bfh[j], t);
      }
  }

  // C/D layout: col = lane&15, row = (lane>>4)*4 + reg
  const int col  = lane & 15;
  const int quad = lane >> 4;
#pragma unroll
  for (int i = 0; i < 4; i++)
#pragma unroll
    for (int j = 0; j < 4; j++)
#pragma unroll
      for (int r = 0; r < 4; r++){
        int row = m0 + wm + i*16 + quad*4 + r;
        int c   = n0 + wn + j*16 + col;
        float v = acc[i][j][r] * alpha;
        if constexpr (OUTMODE == 0){
          u16b h, l; split2(v, h, l);
          Ch[(size_t)row * N + c] = h;
          Cl[(size_t)row * N + c] = l;
        } else {
          Cf[(size_t)row * N + c] = v;
        }
      }
}

// ---------------------------------------------------------------------------
// eta/theta skinny projection (pure f32): per (b,t) row, 32 dots of 2048.
// ---------------------------------------------------------------------------
__global__ __launch_bounds__(256) void etatheta_kernel(
    const float* __restrict__ x, const float* __restrict__ Weta,
    const float* __restrict__ Wtheta, float* __restrict__ eta, float* __restrict__ theta)
{
  __shared__ float xr[2048];
  const int bt = blockIdx.x;
  const int b = bt >> 12, t = bt & 4095;
  const float* xp = x + (size_t)bt * 2048;
  for (int i = threadIdx.x; i < 2048; i += 256) xr[i] = xp[i];
  __syncthreads();
  const int wid = threadIdx.x >> 6, lane = threadIdx.x & 63;
  for (int oi = 0; oi < 8; oi++){
    int og = wid*8 + oi;
    const float* wrow = (og < 16) ? (Weta + (size_t)og*2048)
                                  : (Wtheta + (size_t)(og-16)*2048);
    float acc = 0.f;
    for (int d = lane; d < 2048; d += 64) acc += xr[d] * wrow[d];
#pragma unroll
    for (int off = 32; off; off >>= 1) acc += __shfl_down(acc, off);
    if (lane == 0){
      float s = 1.f / (1.f + expf(-acc));
      if (og < 16) eta  [((size_t)(b*16 + og     ))*4096 + t] = s;
      else         theta[((size_t)(b*16 + og - 16))*4096 + t] = 0.1f * s;
    }
  }
}

// ---------------------------------------------------------------------------
// Decay precompute: per (bh, chunk) of 64 t: lec = cumsum(log eta),
// elt = exp(lec), wt = exp(lec63 - lec) * theta. Removes log/exp/shfl-scan
// from the scan's serial critical path.
// ---------------------------------------------------------------------------
__global__ __launch_bounds__(64) void decay_kernel(
    const float* __restrict__ eta, const float* __restrict__ th,
    float* __restrict__ lecb, float* __restrict__ eltb, float* __restrict__ wtb)
{
  const int bh = blockIdx.x, n = blockIdx.y, lane = threadIdx.x;
  size_t idx = (size_t)bh*4096 + n*64 + lane;
  float cum = logf(fmaxf(eta[idx], 1e-8f));
#pragma unroll
  for (int off = 1; off < 64; off <<= 1){
    float o = __shfl_up(cum, off);
    if (lane >= off) cum += o;
  }
  float lec63 = __shfl(cum, 63);
  lecb[idx] = cum;
  eltb[idx] = expf(cum);
  wtb[idx]  = expf(lec63 - cum) * th[idx];
}

// ---------------------------------------------------------------------------
// Chunk scan v2. Grid (B*H, V/32), block 512 = 8 waves (tw = wid&3 t-block,
// jh = wid>>2 j/v-half). Per chunk:
//   e = kW^T - v | qk = qk^T | zq = qW^T | S = qk*beta*th (tril) |
//   z = elt*zq - S@e (in-place over v) | dw = (wt*e)^T k via kT LDS copy |
//   W <- W*elt63 - dw.  All matmuls 3-term split-bf16.
// LDS ~134 KB; kT staged with rotated writes (bank-spread), v_s stride 36,
// W stride 136. Decay factors read from precomputed global arrays.
// ---------------------------------------------------------------------------
#define WSTR 136
__global__ __launch_bounds__(512) void scan_kernel(
    const u16b* __restrict__ qh, const u16b* __restrict__ ql,
    const u16b* __restrict__ kh, const u16b* __restrict__ kl,
    const float* __restrict__ lecb, const float* __restrict__ eltb,
    const float* __restrict__ wtb,  const float* __restrict__ thb,
    float* vo)                                     // v in, outs out (aliased)
{
  __shared__ u16b kh_s[64*128], kl_s[64*128];
  __shared__ u16b kTh_s[128*72], kTl_s[128*72];
  __shared__ u16b Wh[32*WSTR], Wl[32*WSTR];
  __shared__ u16b eh_s [32*72], el_s [32*72];
  __shared__ u16b ewh_s[32*72], ewl_s[32*72];
  __shared__ u16b Sh_s [64*72], Sl_s [64*72];
  __shared__ float v_s[64*36];
  __shared__ float dec_s[4*64];    // [0]=lec [1]=elt [2]=wt [3]=th

  const int bh = blockIdx.x;
  const int b = bh >> 4, h = bh & 15;
  const int v0 = blockIdx.y * 32;
  const int tid  = threadIdx.x;
  const int wid  = tid >> 6;       // 0..7
  const int tw   = wid & 3;        // t 16-row block
  const int jh   = wid >> 2;       // j/v 16-col half
  const int lane = tid & 63;
  const int rw = lane & 15;
  const int kq = (lane >> 4) * 8;
  const int ccol  = lane & 15;
  const int cquad = lane >> 4;

  for (int i = tid; i < 32*WSTR; i += 512){ Wh[i] = 0; Wl[i] = 0; }

  const size_t rowbase = (size_t)b * 4096;
  const size_t decbase = (size_t)bh * 4096;
  const int sr0 = tid >> 4;             // staging row (it=0), +32 for it=1
  const int sc8 = (tid & 15) * 8;       // staging col
  const int rot = ((tid & 15) + ((lane >> 4) << 1)) & 7;

  for (int n = 0; n < 64; n++){
    const int tbase = n * 64;
    __syncthreads();                    // prev chunk LDS reads + W update done

    // ---- stage k hi/lo rows + transposed kT (rotated writes) ----
#pragma unroll
    for (int it = 0; it < 2; it++){
      int r = it*32 + sr0;
      size_t g = (rowbase + tbase + r) * 2048 + (size_t)h*128 + sc8;
      uint4 uh = *(const uint4*)&kh[g];
      uint4 ul = *(const uint4*)&kl[g];
      *(uint4*)&kh_s[r*128 + sc8] = uh;
      *(uint4*)&kl_s[r*128 + sc8] = ul;
      const u16b* ph = (const u16b*)&uh;
      const u16b* pl = (const u16b*)&ul;
#pragma unroll
      for (int s = 0; s < 8; s++){
        int i = (s + rot) & 7;
        kTh_s[(sc8 + i)*72 + r] = ph[i];
        kTl_s[(sc8 + i)*72 + r] = pl[i];
      }
    }
    { // ---- v: 64x32 f32 coalesced ----
      int r = tid >> 3, c4 = (tid & 7) * 4;
      size_t g = (rowbase + tbase + r) * 2048 + (size_t)h*128 + v0 + c4;
      *(float4*)&v_s[r*36 + c4] = *(const float4*)&vo[g];
    }
    if (tid < 256){ // ---- decay factors ----
      const float* srcs[4] = {lecb, eltb, wtb, thb};
      dec_s[tid] = srcs[tid >> 6][decbase + tbase + (tid & 63)];
    }
    // ---- q fragments (global, L3-warm), rows tw*16+rw ----
    const size_t qg = (rowbase + tbase + tw*16 + rw) * 2048 + (size_t)h*128;
    bf16x8 qah[4], qal[4];
#pragma unroll
    for (int ks = 0; ks < 4; ks++){
      qah[ks] = *(const bf16x8*)(qh + qg + ks*32 + kq);
      qal[ks] = *(const bf16x8*)(ql + qg + ks*32 + kq);
    }
    __syncthreads();

    // ---- e = k @ W^T (rows tw, cols jh-half), 3-term ----
    f32x4 eacc = {};
#pragma unroll
    for (int ks = 0; ks < 4; ks++){
      bf16x8 ah  = *(const bf16x8*)&kh_s[(tw*16 + rw)*128 + ks*32 + kq];
      bf16x8 al  = *(const bf16x8*)&kl_s[(tw*16 + rw)*128 + ks*32 + kq];
      bf16x8 bh_ = *(const bf16x8*)&Wh[(jh*16 + rw)*WSTR + ks*32 + kq];
      bf16x8 bl_ = *(const bf16x8*)&Wl[(jh*16 + rw)*WSTR + ks*32 + kq];
      f32x4 t = mfma16(al, bh_, eacc);
      t = mfma16(ah, bl_, t);
      eacc = mfma16(ah, bh_, t);
    }
    // ---- qk (2 tiles: j4 = jh*2 + j2) and zq (1 tile) ----
    f32x4 qkacc[2] = {};
    f32x4 zqacc = {};
#pragma unroll
    for (int ks = 0; ks < 4; ks++){
#pragma unroll
      for (int j2 = 0; j2 < 2; j2++){
        int j4 = jh*2 + j2;
        bf16x8 bh_ = *(const bf16x8*)&kh_s[(j4*16 + rw)*128 + ks*32 + kq];
        bf16x8 bl_ = *(const bf16x8*)&kl_s[(j4*16 + rw)*128 + ks*32 + kq];
        f32x4 t = mfma16(qal[ks], bh_, qkacc[j2]);
        t = mfma16(qah[ks], bl_, t);
        qkacc[j2] = mfma16(qah[ks], bh_, t);
      }
      bf16x8 wh_ = *(const bf16x8*)&Wh[(jh*16 + rw)*WSTR + ks*32 + kq];
      bf16x8 wl_ = *(const bf16x8*)&Wl[(jh*16 + rw)*WSTR + ks*32 + kq];
      f32x4 t = mfma16(qal[ks], wh_, zqacc);
      t = mfma16(qah[ks], wl_, t);
      zqacc = mfma16(qah[ks], wh_, t);
    }
    // ---- e finalize: e -= v, split-store e^T and (wt*e)^T ----
#pragma unroll
    for (int r = 0; r < 4; r++){
      int t  = tw*16 + cquad*4 + r;
      int vv = jh*16 + ccol;
      float e = eacc[r] - v_s[t*36 + vv];
      u16b h1, l1; split2(e, h1, l1);
      eh_s[vv*72 + t] = h1;  el_s[vv*72 + t] = l1;
      float ew = e * dec_s[128 + t];
      u16b h2, l2; split2(ew, h2, l2);
      ewh_s[vv*72 + t] = h2; ewl_s[vv*72 + t] = l2;
    }
    // ---- S = qk * beta * th[j], tril, split store ----
#pragma unroll
    for (int j2 = 0; j2 < 2; j2++)
#pragma unroll
      for (int r = 0; r < 4; r++){
        int t  = tw*16 + cquad*4 + r;
        int jj = (jh*2 + j2)*16 + ccol;
        float s = 0.f;
        if (jj <= t)
          s = qkacc[j2][r] * __expf(fminf(dec_s[t] - dec_s[jj], 0.f)) * dec_s[192 + jj];
        u16b h1, l1; split2(s, h1, l1);
        Sh_s[t*72 + jj] = h1;  Sl_s[t*72 + jj] = l1;
      }
    __syncthreads();                    // e/ew/S visible to all waves

    // ---- Se = S @ e (rows tw, cols jh-half) ----
    f32x4 seacc = {};
#pragma unroll
    for (int ks2 = 0; ks2 < 2; ks2++){
      bf16x8 ah  = *(const bf16x8*)&Sh_s[(tw*16 + rw)*72 + ks2*32 + kq];
      bf16x8 al  = *(const bf16x8*)&Sl_s[(tw*16 + rw)*72 + ks2*32 + kq];
      bf16x8 bh_ = *(const bf16x8*)&eh_s[(jh*16 + rw)*72 + ks2*32 + kq];
      bf16x8 bl_ = *(const bf16x8*)&el_s[(jh*16 + rw)*72 + ks2*32 + kq];
      f32x4 t = mfma16(al, bh_, seacc);
      t = mfma16(ah, bl_, t);
      seacc = mfma16(ah, bh_, t);
    }
    // ---- z -> vo in place (stores are fire-and-forget) ----
#pragma unroll
    for (int r = 0; r < 4; r++){
      int t  = tw*16 + cquad*4 + r;
      int vv = jh*16 + ccol;
      float z = dec_s[64 + t]*zqacc[r] - seacc[r];
      vo[((rowbase + tbase + t)*16 + h)*128 + v0 + vv] = z;
    }
    // ---- dw: A = ew^T rows (mi), B = kT rows (kcol = wid*16 + rw) ----
    f32x4 dwacc[2] = {};
    const int kcol = wid*16 + rw;
#pragma unroll
    for (int ks2 = 0; ks2 < 2; ks2++){
      bf16x8 bh_ = *(const bf16x8*)&kTh_s[kcol*72 + ks2*32 + kq];
      bf16x8 bl_ = *(const bf16x8*)&kTl_s[kcol*72 + ks2*32 + kq];
#pragma unroll
      for (int mi = 0; mi < 2; mi++){
        bf16x8 amh = *(const bf16x8*)&ewh_s[(mi*16 + rw)*72 + ks2*32 + kq];
        bf16x8 aml = *(const bf16x8*)&ewl_s[(mi*16 + rw)*72 + ks2*32 + kq];
        f32x4 t = mfma16(aml, bh_, dwacc[mi]);
        t = mfma16(amh, bl_, t);
        dwacc[mi] = mfma16(amh, bh_, t);
      }
    }
    // ---- W <- W*elt63 - dw (8 disjoint elems/lane) ----
    float dfac = dec_s[64 + 63];
#pragma unroll
    for (int mi = 0; mi < 2; mi++)
#pragma unroll
      for (int r = 0; r < 4; r++){
        int vv = mi*16 + cquad*4 + r;
        int kk = wid*16 + ccol;
        int idx = vv*WSTR + kk;
        float w = bf2f(Wh[idx]) + bf2f(Wl[idx]);
        w = w*dfac - dwacc[mi][r];
        u16b h1, l1; split2(w, h1, l1);
        Wh[idx] = h1; Wl[idx] = l1;
      }
  }
}
#undef WSTR

// ---------------------------------------------------------------------------
// Gated RMSNorm, f32 in -> split bf16 out.
// ---------------------------------------------------------------------------
__global__ __launch_bounds__(256) void norm_kernel(
    const float* __restrict__ outs, const float* __restrict__ g,
    const float* __restrict__ nw, u16b* __restrict__ ogh, u16b* __restrict__ ogl)
{
  const int bt = blockIdx.x;
  const int tid = threadIdx.x;
  size_t base = (size_t)bt*2048 + (size_t)tid*8;
  float4 x0 = *(const float4*)(outs + base);
  float4 x1 = *(const float4*)(outs + base + 4);
  float x[8] = {x0.x,x0.y,x0.z,x0.w,x1.x,x1.y,x1.z,x1.w};
  float ss = 0.f;
#pragma unroll
  for (int i = 0; i < 8; i++) ss += x[i]*x[i];
#pragma unroll
  for (int off = 1; off < 16; off <<= 1) ss += __shfl_xor(ss, off);  // 16-lane head
  float rs = rsqrtf(ss*(1.f/128.f) + 1e-5f);
  float4 g0 = *(const float4*)(g + base);
  float4 g1 = *(const float4*)(g + base + 4);
  float gg[8] = {g0.x,g0.y,g0.z,g0.w,g1.x,g1.y,g1.z,g1.w};
  int nwb = (tid & 15)*8;
  u16b oh[8], ol[8];
#pragma unroll
  for (int i = 0; i < 8; i++){
    float sig = 1.f / (1.f + __expf(-gg[i]));
    float v = x[i]*rs*nw[nwb+i]*gg[i]*sig;
    split2(v, oh[i], ol[i]);
  }
  *(uint4*)(ogh + base) = *(const uint4*)oh;
  *(uint4*)(ogl + base) = *(const uint4*)ol;
}

// ---------------------------------------------------------------------------
extern "C" void kernel_launch(void* const* d_in, const int* in_sizes, int n_in,
                              void* d_out, int out_size, void* d_ws, size_t ws_size,
                              hipStream_t stream)
{
  (void)in_sizes; (void)n_in; (void)out_size; (void)ws_size;
  const float* x    = (const float*)d_in[0];
  const float* Wq   = (const float*)d_in[1];
  const float* Wk   = (const float*)d_in[2];
  const float* Wv   = (const float*)d_in[3];
  const float* Weta = (const float*)d_in[4];
  const float* Wth  = (const float*)d_in[5];
  const float* Wg   = (const float*)d_in[6];
  const float* nw   = (const float*)d_in[7];
  const float* Wo   = (const float*)d_in[8];
  float* out = (float*)d_out;

  const size_t SZ = (size_t)8192*2048;      // activation elems
  const size_t DS = (size_t)2*16*4096;      // decay arrays (B,H,T)
  u16b* ws = (u16b*)d_ws;
  u16b* qhb = ws;            u16b* qlb = qhb + SZ;
  u16b* khb = qlb + SZ;      u16b* klb = khb + SZ;
  float* vob  = (float*)(klb + SZ);         // v, then outs in place
  float* etab = vob + SZ;
  float* thb  = etab + DS;
  float* lecb = thb  + DS;
  float* eltb = lecb + DS;
  float* wtb  = eltb + DS;
  float* gfb  = (float*)khb;                // g f32 after scan (spans kh+kl)
  u16b* ogh = qhb; u16b* ogl = qlb;         // og reuses q slot

  dim3 gg(16, 64);
  etatheta_kernel<<<8192, 256, 0, stream>>>(x, Weta, Wth, etab, thb);
  decay_kernel<<<dim3(32,64), 64, 0, stream>>>(etab, thb, lecb, eltb, wtb);
  gemm3<0,0><<<gg, 256, 0, stream>>>(x, nullptr, nullptr, Wq, qhb, qlb, nullptr,
                                     8192, 2048, 2048, 0.08838834764831843f);
  gemm3<0,0><<<gg, 256, 0, stream>>>(x, nullptr, nullptr, Wk, khb, klb, nullptr,
                                     8192, 2048, 2048, 1.f);
  gemm3<0,1><<<gg, 256, 0, stream>>>(x, nullptr, nullptr, Wv, nullptr, nullptr, vob,
                                     8192, 2048, 2048, 1.f);
  scan_kernel<<<dim3(32,4), 512, 0, stream>>>(qhb, qlb, khb, klb,
                                              lecb, eltb, wtb, thb, vob);
  gemm3<0,1><<<gg, 256, 0, stream>>>(x, nullptr, nullptr, Wg, nullptr, nullptr, gfb,
                                     8192, 2048, 2048, 1.f);
  norm_kernel<<<8192, 256, 0, stream>>>(vob, gfb, nw, ogh, ogl);
  gemm3<1,1><<<gg, 256, 0, stream>>>(nullptr, ogh, ogl, Wo, nullptr, nullptr, out,
                                     8192, 2048, 2048, 1.f);
}